// Round 9
// baseline (318.822 us; speedup 1.0000x reference)
//
#include <hip/hip_runtime.h>
#include <hip/hip_cooperative_groups.h>
#include <hip/hip_fp16.h>
#include <math.h>

namespace cg = cooperative_groups;

#define N_NODES 100000
#define N_EDGES 1600000
#define D_FEAT  64

#define NPB     256                                // nodes per bucket (dst>>8)
#define NBC     ((N_NODES + NPB - 1) / NPB)        // 391 buckets
#define HIST_WGS 256                               // chunking WGs for hist/bucketize
#define NV4     (N_EDGES / 4)                      // 400000 int4 edge groups
#define CHUNK4  ((NV4 + HIST_WGS - 1) / HIST_WGS)  // 1563 int4s per WG
#define RAW_CAP 5120                               // 10 regs/thread * 512
#define CASTN   ((N_NODES * D_FEAT) / 4)           // 1.6M float4 groups
#define GRID_PRE NBC                               // 391 blocks, 512 threads

// cast slices: 2 batches x 135 blocks x 12 iters x 512 f4 = 1,658,880 >= CASTN
#define CAST_BLKS  (GRID_PRE - HIST_WGS)           // 135
#define CAST_ITERS 12

// LDS arena (ints): phase4 needs buf[5120]+cnt[256]+off[256]+wsum[8] = 5640
#define SMEM_INTS 5640

#define GCAP    68   // staged neighbors per node; 68 ints => 16B-aligned rows

// ---- helpers ------------------------------------------------------------

__device__ __forceinline__ void cast_slice(const float* __restrict__ feat,
                                           __half* __restrict__ feat_h, int i) {
    if (i < CASTN) {
        float4 v = ((const float4*)feat)[i];
        __half2 h0 = __floats2half2_rn(v.x, v.y);
        __half2 h1 = __floats2half2_rn(v.z, v.w);
        uint2 st;
        st.x = *(unsigned*)&h0;
        st.y = *(unsigned*)&h1;
        ((uint2*)feat_h)[i] = st;
    }
}

__device__ __forceinline__ void cast_batch(const float* __restrict__ feat,
                                           __half* __restrict__ feat_h,
                                           int batch, int blk, int t) {
    #pragma unroll
    for (int it = 0; it < CAST_ITERS; ++it)
        cast_slice(feat, feat_h,
                   ((batch * CAST_BLKS + blk) * CAST_ITERS + it) * 512 + t);
}

__device__ __forceinline__ uint4 pack8(const float* v) {
    __half2 h0 = __floats2half2_rn(v[0], v[1]);
    __half2 h1 = __floats2half2_rn(v[2], v[3]);
    __half2 h2 = __floats2half2_rn(v[4], v[5]);
    __half2 h3 = __floats2half2_rn(v[6], v[7]);
    uint4 st;
    st.x = *(unsigned*)&h0; st.y = *(unsigned*)&h1;
    st.z = *(unsigned*)&h2; st.w = *(unsigned*)&h3;
    return st;
}

__device__ __forceinline__ void unp8(uint4 u, float* a) {
    { __half2 h = *(__half2*)&u.x; float2 f = __half22float2(h); a[0]=f.x; a[1]=f.y; }
    { __half2 h = *(__half2*)&u.y; float2 f = __half22float2(h); a[2]=f.x; a[3]=f.y; }
    { __half2 h = *(__half2*)&u.z; float2 f = __half22float2(h); a[4]=f.x; a[5]=f.y; }
    { __half2 h = *(__half2*)&u.w; float2 f = __half22float2(h); a[6]=f.x; a[7]=f.y; }
}

__device__ __forceinline__ void acc4(uint4 u, __half2& h0, __half2& h1,
                                     __half2& h2, __half2& h3) {
    h0 = __hadd2(h0, *(__half2*)&u.x);
    h1 = __hadd2(h1, *(__half2*)&u.y);
    h2 = __hadd2(h2, *(__half2*)&u.z);
    h3 = __hadd2(h3, *(__half2*)&u.w);
}

// block-wide exclusive scan over 512 ints (wsum = 8-int LDS).
// Contains one __syncthreads after the wsum store. ALL 512 threads must call.
__device__ __forceinline__ int block_excl_scan_512(int v, int t, int* wsum) {
    int lane = t & 63, wv = t >> 6;
    int incl = v;
    #pragma unroll
    for (int m = 1; m < 64; m <<= 1) {
        int o = __shfl_up(incl, m);
        if (lane >= m) incl += o;
    }
    if (lane == 63) wsum[wv] = incl;
    __syncthreads();
    int prefix = 0;
    #pragma unroll
    for (int j = 0; j < 8; j++)
        if (j < wv) prefix += wsum[j];
    return prefix + incl - v;
}

// ---- pre-chain phase bodies (round-7 proven, shared coop/fallback) ------

__device__ void phase_hist(int b, int t, int* smem,
                           const int4* __restrict__ dst4,
                           int* __restrict__ percnt) {
    int* cnt = smem;                       // NBC ints
    for (int i = t; i < NBC; i += 512) cnt[i] = 0;
    __syncthreads();
    int i0 = b * CHUNK4;
    int i1 = min(i0 + CHUNK4, NV4);
    for (int i = i0 + t; i < i1; i += 512) {
        int4 d = dst4[i];
        atomicAdd(&cnt[d.x >> 8], 1);
        atomicAdd(&cnt[d.y >> 8], 1);
        atomicAdd(&cnt[d.z >> 8], 1);
        atomicAdd(&cnt[d.w >> 8], 1);
    }
    __syncthreads();
    for (int i = t; i < NBC; i += 512)
        percnt[b * NBC + i] = cnt[i];      // row-contiguous flush
}

__device__ void phase_colscan(int b, int t, int* smem,
                              const int* __restrict__ percnt,
                              int* __restrict__ pexcl,
                              int* __restrict__ bhist) {
    int* wsum = smem;                      // 8 ints
    int v = (t < HIST_WGS) ? percnt[t * NBC + b] : 0;
    int excl = block_excl_scan_512(v, t, wsum);
    if (t < HIST_WGS) pexcl[b * HIST_WGS + t] = excl;
    if (t == HIST_WGS - 1) bhist[b] = excl + v;
}

__device__ void phase_bucketize(int b, int t, int* smem,
                                const int4* __restrict__ src4,
                                const int4* __restrict__ dst4,
                                const int* __restrict__ bhist,
                                const int* __restrict__ pexcl,
                                unsigned int* __restrict__ tmp1) {
    int* base = smem;                      // NBC
    int* cur  = smem + NBC;                // NBC
    int* wsum = smem + 2 * NBC;            // 8
    int v = (t < NBC) ? bhist[t] : 0;
    int excl = block_excl_scan_512(v, t, wsum);
    if (t < NBC) {
        base[t] = excl + pexcl[t * HIST_WGS + b];
        cur[t] = 0;
    }
    __syncthreads();
    int i0 = b * CHUNK4;
    int i1 = min(i0 + CHUNK4, NV4);
    for (int i = i0 + t; i < i1; i += 512) {
        int4 d = dst4[i];
        int4 s = src4[i];
        {
            int bb = d.x >> 8; int r = atomicAdd(&cur[bb], 1);
            tmp1[base[bb] + r] = ((unsigned)s.x << 8) | (unsigned)(d.x & 255);
        }
        {
            int bb = d.y >> 8; int r = atomicAdd(&cur[bb], 1);
            tmp1[base[bb] + r] = ((unsigned)s.y << 8) | (unsigned)(d.y & 255);
        }
        {
            int bb = d.z >> 8; int r = atomicAdd(&cur[bb], 1);
            tmp1[base[bb] + r] = ((unsigned)s.z << 8) | (unsigned)(d.z & 255);
        }
        {
            int bb = d.w >> 8; int r = atomicAdd(&cur[bb], 1);
            tmp1[base[bb] + r] = ((unsigned)s.w << 8) | (unsigned)(d.w & 255);
        }
    }
}

__device__ void phase_csr(int b, int t, int* smem,
                          const unsigned int* __restrict__ tmp1,
                          const int* __restrict__ bhist,
                          int* __restrict__ offsets,
                          int* __restrict__ csr_src) {
    int* buf  = smem;                      // RAW_CAP
    int* cnt  = smem + RAW_CAP;            // NPB
    int* off  = smem + RAW_CAP + NPB;      // NPB
    int* wsum = smem + RAW_CAP + 2 * NPB;  // 8
    int sObase, sEcnt;

    {   // ebase[b] = exclusive prefix of bhist at index b (replicated scan)
        int v = (t < NBC) ? bhist[t] : 0;
        int ex = block_excl_scan_512(v, t, wsum);
        // broadcast thread b's values via LDS
        if (t == b) { wsum[0] = ex; wsum[1] = v; }
        __syncthreads();
        sObase = wsum[0]; sEcnt = wsum[1];
    }
    if (t < NPB) cnt[t] = 0;
    __syncthreads();
    int ebase = sObase;
    int ecnt  = sEcnt;
    const unsigned int* ebuf = tmp1 + ebase;
    int node0 = b * NPB;

    unsigned myv[10];
    #pragma unroll
    for (int k = 0; k < 10; k++) {
        int i = t + k * 512;
        if (i < ecnt) {
            unsigned u = ebuf[i];
            myv[k] = u;
            atomicAdd(&cnt[u & 255], 1);
        }
    }
    __syncthreads();

    int v = (t < NPB) ? cnt[t] : 0;
    int excl = block_excl_scan_512(v, t, wsum);
    if (t < NPB) {
        off[t] = excl;
        cnt[t] = 0;  // reuse as cursor
        if (node0 + t < N_NODES) offsets[node0 + t] = ebase + excl;
    }
    if (b == NBC - 1 && t == 0) offsets[N_NODES] = N_EDGES;
    __syncthreads();

    #pragma unroll
    for (int k = 0; k < 10; k++) {
        int i = t + k * 512;
        if (i < ecnt) {
            unsigned u = myv[k];
            int d = (int)(u & 255);
            int r = atomicAdd(&cnt[d], 1);
            buf[off[d] + r] = (int)(u >> 8);
        }
    }
    __syncthreads();
    for (int i = t; i < ecnt; i += 512)
        csr_src[ebase + i] = buf[i];
}

// ---- cooperative mega-kernel: hist -> colscan -> bucketize -> sort ------
// 391 blocks x 512 threads (co-resident: 4 blocks/CU by threads, 22.6KB LDS).
// Cast interleaved into the 135 non-hist blocks of phases 1 and 3.

__global__ __launch_bounds__(512) void pre_coop(
        const int4* __restrict__ src4,
        const int4* __restrict__ dst4,
        const float* __restrict__ feat,
        __half* __restrict__ feat_h,
        int* __restrict__ percnt,
        int* __restrict__ pexcl,
        int* __restrict__ bhist,
        int* __restrict__ offsets,
        unsigned int* __restrict__ tmp1,
        int* __restrict__ csr_src) {
    __shared__ int smem[SMEM_INTS];
    cg::grid_group grid = cg::this_grid();
    int b = blockIdx.x, t = threadIdx.x;

    if (b < HIST_WGS) phase_hist(b, t, smem, dst4, percnt);
    else              cast_batch(feat, feat_h, 0, b - HIST_WGS, t);
    grid.sync();

    phase_colscan(b, t, smem, percnt, pexcl, bhist);
    grid.sync();

    if (b < HIST_WGS) phase_bucketize(b, t, smem, src4, dst4, bhist, pexcl, tmp1);
    else              cast_batch(feat, feat_h, 1, b - HIST_WGS, t);
    grid.sync();

    phase_csr(b, t, smem, tmp1, bhist, offsets, csr_src);
}

// ---- fallback path (round-7 equivalent, used if coop launch fails) ------

__global__ __launch_bounds__(512) void pre_p1(const int4* __restrict__ dst4,
                                              int* __restrict__ percnt) {
    __shared__ int smem[NBC];
    phase_hist(blockIdx.x, threadIdx.x, smem, dst4, percnt);
}
__global__ __launch_bounds__(512) void pre_p2(const int* __restrict__ percnt,
                                              int* __restrict__ pexcl,
                                              int* __restrict__ bhist) {
    __shared__ int smem[8];
    phase_colscan(blockIdx.x, threadIdx.x, smem, percnt, pexcl, bhist);
}
__global__ __launch_bounds__(512) void pre_p3(const int4* __restrict__ src4,
                                              const int4* __restrict__ dst4,
                                              const int* __restrict__ bhist,
                                              const int* __restrict__ pexcl,
                                              unsigned int* __restrict__ tmp1) {
    __shared__ int smem[2 * NBC + 8];
    phase_bucketize(blockIdx.x, threadIdx.x, smem, src4, dst4, bhist, pexcl, tmp1);
}
__global__ __launch_bounds__(512) void pre_p4(const unsigned int* __restrict__ tmp1,
                                              const int* __restrict__ bhist,
                                              int* __restrict__ offsets,
                                              int* __restrict__ csr_src) {
    __shared__ int smem[SMEM_INTS];
    phase_csr(blockIdx.x, threadIdx.x, smem, tmp1, bhist, offsets, csr_src);
}
__global__ __launch_bounds__(512) void cast_kernel(const float* __restrict__ feat,
                                                   __half* __restrict__ feat_h) {
    cast_slice(feat, feat_h, blockIdx.x * 512 + threadIdx.x);
}

// ---- Gather passes: 8 nodes per wave, 8 lanes per node, 4x unrolled -----

__global__ __launch_bounds__(256) void gather1_kernel(
        const __half* __restrict__ feat_h,
        const int* __restrict__ offsets,
        const int* __restrict__ csr,
        __half* __restrict__ x1_h) {
    __shared__ int snbr[4][8][GCAP];
    int wv   = threadIdx.x >> 6;
    int lane = threadIdx.x & 63;
    int g    = lane >> 3;          // node sub-index within wave
    int fl   = lane & 7;           // feature octet index
    int node = (blockIdx.x * 4 + wv) * 8 + g;   // 3125*32 == 100000 exactly

    int base = offsets[node];
    int deg  = offsets[node + 1] - base;
    int dcap = min(deg, GCAP);

    int* my = snbr[wv][g];
    for (int j = fl; j < dcap; j += 8)
        my[j] = csr[base + j];
    __builtin_amdgcn_wave_barrier();

    __half2 a0 = __float2half2_rn(0.f), a1 = a0, a2 = a0, a3 = a0;
    __half2 b0 = a0, b1 = a0, b2 = a0, b3 = a0;
    const __half* fb = feat_h + (fl << 3);
    int j = 0;
    for (; j + 4 <= dcap; j += 4) {
        int4 s = *(const int4*)&my[j];          // ds_read_b128, group-broadcast
        uint4 u0 = *(const uint4*)(fb + ((size_t)s.x << 6));
        uint4 u1 = *(const uint4*)(fb + ((size_t)s.y << 6));
        uint4 u2 = *(const uint4*)(fb + ((size_t)s.z << 6));
        uint4 u3 = *(const uint4*)(fb + ((size_t)s.w << 6));
        acc4(u0, a0, a1, a2, a3);
        acc4(u1, b0, b1, b2, b3);
        acc4(u2, a0, a1, a2, a3);
        acc4(u3, b0, b1, b2, b3);
    }
    for (; j < dcap; ++j) {
        int s = my[j];
        uint4 u = *(const uint4*)(fb + ((size_t)s << 6));
        acc4(u, a0, a1, a2, a3);
    }
    for (j = GCAP; j < deg; ++j) {              // rare overflow fallback
        int s = csr[base + j];
        uint4 u = *(const uint4*)(fb + ((size_t)s << 6));
        acc4(u, a0, a1, a2, a3);
    }
    a0 = __hadd2(a0, b0); a1 = __hadd2(a1, b1);
    a2 = __hadd2(a2, b2); a3 = __hadd2(a3, b3);

    float invf = (deg > 0) ? __builtin_amdgcn_rcpf((float)deg) : 0.0f;
    float r[8];
    { float2 f = __half22float2(a0); r[0]=f.x*invf; r[1]=f.y*invf; }
    { float2 f = __half22float2(a1); r[2]=f.x*invf; r[3]=f.y*invf; }
    { float2 f = __half22float2(a2); r[4]=f.x*invf; r[5]=f.y*invf; }
    { float2 f = __half22float2(a3); r[6]=f.x*invf; r[7]=f.y*invf; }
    *(uint4*)(x1_h + ((size_t)node << 6) + (fl << 3)) = pack8(r);
}

__global__ __launch_bounds__(256) void gather2_finalize_kernel(
        const __half* __restrict__ x1_h,
        const int* __restrict__ offsets,
        const int* __restrict__ csr,
        float* __restrict__ out) {
    __shared__ int snbr[4][8][GCAP];
    int wv   = threadIdx.x >> 6;
    int lane = threadIdx.x & 63;
    int g    = lane >> 3;
    int fl   = lane & 7;
    int node = (blockIdx.x * 4 + wv) * 8 + g;

    int base = offsets[node];
    int deg  = offsets[node + 1] - base;
    int dcap = min(deg, GCAP);

    int* my = snbr[wv][g];
    for (int j = fl; j < dcap; j += 8)
        my[j] = csr[base + j];
    __builtin_amdgcn_wave_barrier();

    __half2 a0 = __float2half2_rn(0.f), a1 = a0, a2 = a0, a3 = a0;
    __half2 c0 = a0, c1 = a0, c2 = a0, c3 = a0;
    const __half* fb = x1_h + (fl << 3);
    int j = 0;
    for (; j + 4 <= dcap; j += 4) {
        int4 s = *(const int4*)&my[j];
        uint4 u0 = *(const uint4*)(fb + ((size_t)s.x << 6));
        uint4 u1 = *(const uint4*)(fb + ((size_t)s.y << 6));
        uint4 u2 = *(const uint4*)(fb + ((size_t)s.z << 6));
        uint4 u3 = *(const uint4*)(fb + ((size_t)s.w << 6));
        acc4(u0, a0, a1, a2, a3);
        acc4(u1, c0, c1, c2, c3);
        acc4(u2, a0, a1, a2, a3);
        acc4(u3, c0, c1, c2, c3);
    }
    for (; j < dcap; ++j) {
        int s = my[j];
        uint4 u = *(const uint4*)(fb + ((size_t)s << 6));
        acc4(u, a0, a1, a2, a3);
    }
    for (j = GCAP; j < deg; ++j) {
        int s = csr[base + j];
        uint4 u = *(const uint4*)(fb + ((size_t)s << 6));
        acc4(u, a0, a1, a2, a3);
    }
    a0 = __hadd2(a0, c0); a1 = __hadd2(a1, c1);
    a2 = __hadd2(a2, c2); a3 = __hadd2(a3, c3);

    float invf = (deg > 0) ? __builtin_amdgcn_rcpf((float)deg) : 0.0f;
    float b[8];
    { float2 f = __half22float2(a0); b[0]=f.x*invf; b[1]=f.y*invf; }
    { float2 f = __half22float2(a1); b[2]=f.x*invf; b[3]=f.y*invf; }
    { float2 f = __half22float2(a2); b[4]=f.x*invf; b[5]=f.y*invf; }
    { float2 f = __half22float2(a3); b[6]=f.x*invf; b[7]=f.y*invf; }

    float a[8];
    uint4 ua = *(const uint4*)(x1_h + ((size_t)node << 6) + (fl << 3));
    unp8(ua, a);

    float dot = 0.f, nn1 = 0.f, nn2 = 0.f;
    #pragma unroll
    for (int t = 0; t < 8; t++) {
        dot += a[t] * b[t];
        nn1 += a[t] * a[t];
        nn2 += b[t] * b[t];
    }
    #pragma unroll
    for (int m = 1; m < 8; m <<= 1) {     // reduce within the 8-lane group
        dot += __shfl_xor(dot, m);
        nn1 += __shfl_xor(nn1, m);
        nn2 += __shfl_xor(nn2, m);
    }

    float denom = fmaxf(__builtin_amdgcn_sqrtf(nn1 * nn2), 1e-8f);
    float w = dot * __builtin_amdgcn_rcpf(denom);
    float omw = 1.0f - w;

    float4 r0, r1;
    r0.x = w*b[0] + omw*a[0]; r0.y = w*b[1] + omw*a[1];
    r0.z = w*b[2] + omw*a[2]; r0.w = w*b[3] + omw*a[3];
    r1.x = w*b[4] + omw*a[4]; r1.y = w*b[5] + omw*a[5];
    r1.z = w*b[6] + omw*a[6]; r1.w = w*b[7] + omw*a[7];
    float* po = out + ((size_t)node << 6) + (fl << 3);
    *(float4*)po = r0;
    *(float4*)(po + 4) = r1;
}

// ---- launch -------------------------------------------------------------

extern "C" void kernel_launch(void* const* d_in, const int* in_sizes, int n_in,
                              void* d_out, int out_size, void* d_ws, size_t ws_size,
                              hipStream_t stream) {
    const float* feat = (const float*)d_in[0];
    const int*   eidx = (const int*)d_in[1];
    const int4*  src4 = (const int4*)eidx;
    const int4*  dst4 = (const int4*)(eidx + N_EDGES);

    __half*       feat_h  = (__half*)d_ws;                          // 12.8 MB
    __half*       x1_h    = feat_h + (size_t)N_NODES * D_FEAT;      // 12.8 MB
    unsigned int* tmp1    = (unsigned int*)(x1_h + (size_t)N_NODES * D_FEAT); // 6.4 MB
    int*          csr_src = (int*)(tmp1 + N_EDGES);                 // 6.4 MB
    int*          offsets = csr_src + N_EDGES;                      // 100001
    int*          percnt  = offsets + (N_NODES + 1);                // 256*391
    int*          pexcl   = percnt + HIST_WGS * NBC;                // 391*256
    int*          bhist   = pexcl + NBC * HIST_WGS;                 // NBC
    float*        out     = (float*)d_out;

    void* args[] = { (void*)&src4, (void*)&dst4, (void*)&feat, (void*)&feat_h,
                     (void*)&percnt, (void*)&pexcl, (void*)&bhist,
                     (void*)&offsets, (void*)&tmp1, (void*)&csr_src };
    hipError_t err = hipLaunchCooperativeKernel(
        reinterpret_cast<void*>(pre_coop), dim3(GRID_PRE), dim3(512),
        args, 0, stream);

    if (err != hipSuccess) {
        // fallback: round-7-equivalent 4-kernel chain + standalone cast
        cast_kernel<<<(CASTN + 511) / 512, 512, 0, stream>>>(feat, feat_h);
        pre_p1<<<HIST_WGS, 512, 0, stream>>>(dst4, percnt);
        pre_p2<<<NBC,      512, 0, stream>>>(percnt, pexcl, bhist);
        pre_p3<<<HIST_WGS, 512, 0, stream>>>(src4, dst4, bhist, pexcl, tmp1);
        pre_p4<<<NBC,      512, 0, stream>>>(tmp1, bhist, offsets, csr_src);
    }

    int nblocks = N_NODES / 32;   // 3125 exactly (100000 = 3125*32)
    gather1_kernel<<<nblocks, 256, 0, stream>>>(feat_h, offsets, csr_src, x1_h);
    gather2_finalize_kernel<<<nblocks, 256, 0, stream>>>(x1_h, offsets, csr_src, out);
}

// Round 10
// 159.010 us; speedup vs baseline: 2.0050x; 2.0050x over previous
//
#include <hip/hip_runtime.h>
#include <hip/hip_fp16.h>
#include <math.h>

#define N_NODES 100000
#define N_EDGES 1600000
#define D_FEAT  64

#define NPB     256                                // nodes per bucket (dst>>8)
#define NBC     ((N_NODES + NPB - 1) / NPB)        // 391 buckets
#define HIST_WGS 256                               // chunking WGs for hist/bucketize
#define NV4     (N_EDGES / 4)                      // 400000 int4 edge groups
#define CHUNK4  ((NV4 + HIST_WGS - 1) / HIST_WGS)  // 1563 int4s per WG
#define RAW_CAP 5120                               // 10 regs/thread; max bucket ~4350
#define CASTN   ((N_NODES * D_FEAT) / 4)           // 1.6M float4 groups

// cast ballast distribution (block-equivalents; K1/K2 are 256-thread, K3/K4 512)
#define CAST1   2250
#define CAST2   1000
#define CAST3   750
#define CAST4   750
#define CO1     0
#define CO2     (CAST1 * 256)                      // 576000
#define CO3     (CO2 + CAST2 * 256)                // 832000
#define CO4     (CO3 + CAST3 * 512)                // 1216000
// CO4 + CAST4*512 == 1600000 == CASTN exactly

#define GCAP    68   // staged neighbors per node; 68 ints => 16B-aligned rows, distinct banks per group

// ---- helpers ------------------------------------------------------------

__device__ __forceinline__ void cast_slice(const float* __restrict__ feat,
                                           __half* __restrict__ feat_h, int i) {
    if (i < CASTN) {
        float4 v = ((const float4*)feat)[i];
        __half2 h0 = __floats2half2_rn(v.x, v.y);
        __half2 h1 = __floats2half2_rn(v.z, v.w);
        uint2 st;
        st.x = *(unsigned*)&h0;
        st.y = *(unsigned*)&h1;
        ((uint2*)feat_h)[i] = st;
    }
}

__device__ __forceinline__ uint4 pack8(const float* v) {
    __half2 h0 = __floats2half2_rn(v[0], v[1]);
    __half2 h1 = __floats2half2_rn(v[2], v[3]);
    __half2 h2 = __floats2half2_rn(v[4], v[5]);
    __half2 h3 = __floats2half2_rn(v[6], v[7]);
    uint4 st;
    st.x = *(unsigned*)&h0; st.y = *(unsigned*)&h1;
    st.z = *(unsigned*)&h2; st.w = *(unsigned*)&h3;
    return st;
}

__device__ __forceinline__ void unp8(uint4 u, float* a) {
    { __half2 h = *(__half2*)&u.x; float2 f = __half22float2(h); a[0]=f.x; a[1]=f.y; }
    { __half2 h = *(__half2*)&u.y; float2 f = __half22float2(h); a[2]=f.x; a[3]=f.y; }
    { __half2 h = *(__half2*)&u.z; float2 f = __half22float2(h); a[4]=f.x; a[5]=f.y; }
    { __half2 h = *(__half2*)&u.w; float2 f = __half22float2(h); a[6]=f.x; a[7]=f.y; }
}

__device__ __forceinline__ void acc4(uint4 u, __half2& h0, __half2& h1,
                                     __half2& h2, __half2& h3) {
    h0 = __hadd2(h0, *(__half2*)&u.x);
    h1 = __hadd2(h1, *(__half2*)&u.y);
    h2 = __hadd2(h2, *(__half2*)&u.z);
    h3 = __hadd2(h3, *(__half2*)&u.w);
}

// block-wide exclusive scan over 512 ints (wsum = 8-int LDS).
// Contains one __syncthreads after the wsum store.
__device__ __forceinline__ int block_excl_scan_512(int v, int t, int* wsum) {
    int lane = t & 63, wv = t >> 6;
    int incl = v;
    #pragma unroll
    for (int m = 1; m < 64; m <<= 1) {
        int o = __shfl_up(incl, m);
        if (lane >= m) incl += o;
    }
    if (lane == 63) wsum[wv] = incl;
    __syncthreads();
    int prefix = 0;
    #pragma unroll
    for (int j = 0; j < 8; j++)
        if (j < wv) prefix += wsum[j];
    return prefix + incl - v;
}

// block-wide exclusive scan over 256 ints (wsum = 4-int LDS).
__device__ __forceinline__ int block_excl_scan_256(int v, int t, int* wsum) {
    int lane = t & 63, wv = t >> 6;
    int incl = v;
    #pragma unroll
    for (int m = 1; m < 64; m <<= 1) {
        int o = __shfl_up(incl, m);
        if (lane >= m) incl += o;
    }
    if (lane == 63) wsum[wv] = incl;
    __syncthreads();
    int prefix = 0;
    #pragma unroll
    for (int j = 0; j < 4; j++)
        if (j < wv) prefix += wsum[j];
    return prefix + incl - v;
}

// ---- K1: coarse histogram + cast ballast --------------------------------
// blocks [0, HIST_WGS): per-WG LDS bucket histogram over a 6250-edge chunk,
// flushed ROW-CONTIGUOUS to percnt[wg*NBC + b] (dense full-line writes).
// blocks [HIST_WGS, ...): cast slice 1.

__global__ __launch_bounds__(256) void k1_hist_cast(
        const float* __restrict__ feat,
        __half* __restrict__ feat_h,
        const int4* __restrict__ dst4,
        int* __restrict__ percnt) {
    if (blockIdx.x >= HIST_WGS) {
        cast_slice(feat, feat_h, CO1 + (blockIdx.x - HIST_WGS) * 256 + threadIdx.x);
        return;
    }
    __shared__ int cnt[NBC];
    int wg = blockIdx.x, t = threadIdx.x;
    for (int i = t; i < NBC; i += 256) cnt[i] = 0;
    __syncthreads();
    int i0 = wg * CHUNK4;
    int i1 = min(i0 + CHUNK4, NV4);
    for (int i = i0 + t; i < i1; i += 256) {
        int4 d = dst4[i];
        atomicAdd(&cnt[d.x >> 8], 1);
        atomicAdd(&cnt[d.y >> 8], 1);
        atomicAdd(&cnt[d.z >> 8], 1);
        atomicAdd(&cnt[d.w >> 8], 1);
    }
    __syncthreads();
    for (int i = t; i < NBC; i += 256)
        percnt[wg * NBC + i] = cnt[i];
}

// ---- K2: per-bucket column scan + cast ballast --------------------------
// Block b scans cnt[b][wg] over wg=0..255 (strided reads, L2-resident,
// read-only). Prefixes go to pexcl[b*HIST_WGS + wg] (CONTIGUOUS writes —
// no partial-line RMW). Totals -> bhist[b].

__global__ __launch_bounds__(256) void k2_colscan(
        const int* __restrict__ percnt,
        int* __restrict__ pexcl,
        int* __restrict__ bhist,
        const float* __restrict__ feat,
        __half* __restrict__ feat_h) {
    if (blockIdx.x >= NBC) {
        cast_slice(feat, feat_h, CO2 + (blockIdx.x - NBC) * 256 + threadIdx.x);
        return;
    }
    __shared__ int wsum[4];
    int b = blockIdx.x, t = threadIdx.x;
    int v = percnt[t * NBC + b];
    int excl = block_excl_scan_256(v, t, wsum);
    pexcl[b * HIST_WGS + t] = excl;
    if (t == HIST_WGS - 1) bhist[b] = excl + v;
}

// ---- K3: bucketize + cast ballast ---------------------------------------
// WG wg scatters its 6250-edge chunk into tmp1 at base[b] = bbase(b) +
// pexcl[b][wg] + LDS cursor. Per-(wg,bucket) runs avg 16 edges = 64B ->
// full-line writes. bbase derived by an in-block 391-scan of bhist.

__global__ __launch_bounds__(512) void k3_bucketize(
        const int4* __restrict__ src4,
        const int4* __restrict__ dst4,
        const int* __restrict__ bhist,
        const int* __restrict__ pexcl,
        unsigned int* __restrict__ tmp1,
        const float* __restrict__ feat,
        __half* __restrict__ feat_h) {
    if (blockIdx.x >= HIST_WGS) {
        cast_slice(feat, feat_h, CO3 + (blockIdx.x - HIST_WGS) * 512 + threadIdx.x);
        return;
    }
    __shared__ int base[NBC];
    __shared__ int cur[NBC];
    __shared__ int wsum[8];
    int wg = blockIdx.x, t = threadIdx.x;
    int v = (t < NBC) ? bhist[t] : 0;
    int excl = block_excl_scan_512(v, t, wsum);
    if (t < NBC) {
        base[t] = excl + pexcl[t * HIST_WGS + wg];
        cur[t] = 0;
    }
    __syncthreads();
    int i0 = wg * CHUNK4;
    int i1 = min(i0 + CHUNK4, NV4);
    for (int i = i0 + t; i < i1; i += 512) {
        int4 d = dst4[i];
        int4 s = src4[i];
        {
            int b = d.x >> 8; int r = atomicAdd(&cur[b], 1);
            tmp1[base[b] + r] = ((unsigned)s.x << 8) | (unsigned)(d.x & 255);
        }
        {
            int b = d.y >> 8; int r = atomicAdd(&cur[b], 1);
            tmp1[base[b] + r] = ((unsigned)s.y << 8) | (unsigned)(d.y & 255);
        }
        {
            int b = d.z >> 8; int r = atomicAdd(&cur[b], 1);
            tmp1[base[b] + r] = ((unsigned)s.z << 8) | (unsigned)(d.z & 255);
        }
        {
            int b = d.w >> 8; int r = atomicAdd(&cur[b], 1);
            tmp1[base[b] + r] = ((unsigned)s.w << 8) | (unsigned)(d.w & 255);
        }
    }
}

// ---- K4: per-bucket counting sort + cast ballast ------------------------
// SINGLE global read of the bucket's edges into statically-indexed regs
// while histogramming; scan; scatter regs->LDS buf; coalesced write.
// ebase/ecnt derived by in-block 391-scan of bhist.

__global__ __launch_bounds__(512) void k4_bucket_csr(
        const unsigned int* __restrict__ tmp1,
        const int* __restrict__ bhist,
        int* __restrict__ offsets,
        int* __restrict__ csr_src,
        const float* __restrict__ feat,
        __half* __restrict__ feat_h) {
    if (blockIdx.x >= NBC) {
        cast_slice(feat, feat_h, CO4 + (blockIdx.x - NBC) * 512 + threadIdx.x);
        return;
    }
    __shared__ int cnt[NPB];
    __shared__ int off[NPB];
    __shared__ int wsum[8];
    __shared__ int buf[RAW_CAP];
    __shared__ int sEbase, sEcnt;
    int b = blockIdx.x, t = threadIdx.x;

    {   // bbase[b] = exclusive prefix of bhist at index b
        int v = (t < NBC) ? bhist[t] : 0;
        int ex = block_excl_scan_512(v, t, wsum);
        if (t == b) { sEbase = ex; sEcnt = v; }
    }
    if (t < NPB) cnt[t] = 0;
    __syncthreads();
    int ebase = sEbase;
    int ecnt  = sEcnt;
    int node0 = b * NPB;

    if (ecnt <= RAW_CAP) {
        unsigned myv[10];
        #pragma unroll
        for (int k = 0; k < 10; k++) {
            int i = t + k * 512;
            if (i < ecnt) {
                unsigned u = tmp1[ebase + i];
                myv[k] = u;
                atomicAdd(&cnt[u & 255], 1);
            }
        }
        __syncthreads();

        int v = (t < NPB) ? cnt[t] : 0;
        int excl = block_excl_scan_512(v, t, wsum);
        if (t < NPB) {
            off[t] = excl;
            cnt[t] = 0;  // reuse as cursor
            if (node0 + t < N_NODES) offsets[node0 + t] = ebase + excl;
        }
        if (b == NBC - 1 && t == 0) offsets[N_NODES] = N_EDGES;
        __syncthreads();

        #pragma unroll
        for (int k = 0; k < 10; k++) {
            int i = t + k * 512;
            if (i < ecnt) {
                unsigned u = myv[k];
                int d = (int)(u & 255);
                int r = atomicAdd(&cnt[d], 1);
                buf[off[d] + r] = (int)(u >> 8);
            }
        }
        __syncthreads();
        for (int i = t; i < ecnt; i += 512)
            csr_src[ebase + i] = buf[i];
    } else {                                    // never taken for this input
        for (int i = t; i < ecnt; i += 512)
            atomicAdd(&cnt[tmp1[ebase + i] & 255], 1);
        __syncthreads();

        int v = (t < NPB) ? cnt[t] : 0;
        int excl = block_excl_scan_512(v, t, wsum);
        if (t < NPB) {
            off[t] = excl;
            cnt[t] = 0;
            if (node0 + t < N_NODES) offsets[node0 + t] = ebase + excl;
        }
        if (b == NBC - 1 && t == 0) offsets[N_NODES] = N_EDGES;
        __syncthreads();

        for (int i = t; i < ecnt; i += 512) {
            unsigned u = tmp1[ebase + i];
            int d = (int)(u & 255);
            int r = atomicAdd(&cnt[d], 1);
            csr_src[ebase + off[d] + r] = (int)(u >> 8);
        }
    }
}

// ---- Gather passes: 8 nodes per wave, 8 lanes per node, 4x unrolled -----

__global__ __launch_bounds__(256) void gather1_kernel(
        const __half* __restrict__ feat_h,
        const int* __restrict__ offsets,
        const int* __restrict__ csr,
        __half* __restrict__ x1_h) {
    __shared__ int snbr[4][8][GCAP];
    int wv   = threadIdx.x >> 6;
    int lane = threadIdx.x & 63;
    int g    = lane >> 3;          // node sub-index within wave
    int fl   = lane & 7;           // feature octet index
    int node = (blockIdx.x * 4 + wv) * 8 + g;   // 3125*32 == 100000 exactly

    int base = offsets[node];
    int deg  = offsets[node + 1] - base;
    int dcap = min(deg, GCAP);

    int* my = snbr[wv][g];
    for (int j = fl; j < dcap; j += 8)
        my[j] = csr[base + j];
    __builtin_amdgcn_wave_barrier();

    __half2 a0 = __float2half2_rn(0.f), a1 = a0, a2 = a0, a3 = a0;
    __half2 b0 = a0, b1 = a0, b2 = a0, b3 = a0;
    const __half* fb = feat_h + (fl << 3);
    int j = 0;
    for (; j + 4 <= dcap; j += 4) {
        int4 s = *(const int4*)&my[j];          // ds_read_b128, group-broadcast
        uint4 u0 = *(const uint4*)(fb + ((size_t)s.x << 6));
        uint4 u1 = *(const uint4*)(fb + ((size_t)s.y << 6));
        uint4 u2 = *(const uint4*)(fb + ((size_t)s.z << 6));
        uint4 u3 = *(const uint4*)(fb + ((size_t)s.w << 6));
        acc4(u0, a0, a1, a2, a3);
        acc4(u1, b0, b1, b2, b3);
        acc4(u2, a0, a1, a2, a3);
        acc4(u3, b0, b1, b2, b3);
    }
    for (; j < dcap; ++j) {
        int s = my[j];
        uint4 u = *(const uint4*)(fb + ((size_t)s << 6));
        acc4(u, a0, a1, a2, a3);
    }
    for (j = GCAP; j < deg; ++j) {              // rare overflow fallback
        int s = csr[base + j];
        uint4 u = *(const uint4*)(fb + ((size_t)s << 6));
        acc4(u, a0, a1, a2, a3);
    }
    a0 = __hadd2(a0, b0); a1 = __hadd2(a1, b1);
    a2 = __hadd2(a2, b2); a3 = __hadd2(a3, b3);

    float invf = (deg > 0) ? __builtin_amdgcn_rcpf((float)deg) : 0.0f;
    float r[8];
    { float2 f = __half22float2(a0); r[0]=f.x*invf; r[1]=f.y*invf; }
    { float2 f = __half22float2(a1); r[2]=f.x*invf; r[3]=f.y*invf; }
    { float2 f = __half22float2(a2); r[4]=f.x*invf; r[5]=f.y*invf; }
    { float2 f = __half22float2(a3); r[6]=f.x*invf; r[7]=f.y*invf; }
    *(uint4*)(x1_h + ((size_t)node << 6) + (fl << 3)) = pack8(r);
}

__global__ __launch_bounds__(256) void gather2_finalize_kernel(
        const __half* __restrict__ x1_h,
        const int* __restrict__ offsets,
        const int* __restrict__ csr,
        float* __restrict__ out) {
    __shared__ int snbr[4][8][GCAP];
    int wv   = threadIdx.x >> 6;
    int lane = threadIdx.x & 63;
    int g    = lane >> 3;
    int fl   = lane & 7;
    int node = (blockIdx.x * 4 + wv) * 8 + g;

    int base = offsets[node];
    int deg  = offsets[node + 1] - base;
    int dcap = min(deg, GCAP);

    int* my = snbr[wv][g];
    for (int j = fl; j < dcap; j += 8)
        my[j] = csr[base + j];
    __builtin_amdgcn_wave_barrier();

    __half2 a0 = __float2half2_rn(0.f), a1 = a0, a2 = a0, a3 = a0;
    __half2 c0 = a0, c1 = a0, c2 = a0, c3 = a0;
    const __half* fb = x1_h + (fl << 3);
    int j = 0;
    for (; j + 4 <= dcap; j += 4) {
        int4 s = *(const int4*)&my[j];
        uint4 u0 = *(const uint4*)(fb + ((size_t)s.x << 6));
        uint4 u1 = *(const uint4*)(fb + ((size_t)s.y << 6));
        uint4 u2 = *(const uint4*)(fb + ((size_t)s.z << 6));
        uint4 u3 = *(const uint4*)(fb + ((size_t)s.w << 6));
        acc4(u0, a0, a1, a2, a3);
        acc4(u1, c0, c1, c2, c3);
        acc4(u2, a0, a1, a2, a3);
        acc4(u3, c0, c1, c2, c3);
    }
    for (; j < dcap; ++j) {
        int s = my[j];
        uint4 u = *(const uint4*)(fb + ((size_t)s << 6));
        acc4(u, a0, a1, a2, a3);
    }
    for (j = GCAP; j < deg; ++j) {
        int s = csr[base + j];
        uint4 u = *(const uint4*)(fb + ((size_t)s << 6));
        acc4(u, a0, a1, a2, a3);
    }
    a0 = __hadd2(a0, c0); a1 = __hadd2(a1, c1);
    a2 = __hadd2(a2, c2); a3 = __hadd2(a3, c3);

    float invf = (deg > 0) ? __builtin_amdgcn_rcpf((float)deg) : 0.0f;
    float b[8];
    { float2 f = __half22float2(a0); b[0]=f.x*invf; b[1]=f.y*invf; }
    { float2 f = __half22float2(a1); b[2]=f.x*invf; b[3]=f.y*invf; }
    { float2 f = __half22float2(a2); b[4]=f.x*invf; b[5]=f.y*invf; }
    { float2 f = __half22float2(a3); b[6]=f.x*invf; b[7]=f.y*invf; }

    float a[8];
    uint4 ua = *(const uint4*)(x1_h + ((size_t)node << 6) + (fl << 3));
    unp8(ua, a);

    float dot = 0.f, nn1 = 0.f, nn2 = 0.f;
    #pragma unroll
    for (int t = 0; t < 8; t++) {
        dot += a[t] * b[t];
        nn1 += a[t] * a[t];
        nn2 += b[t] * b[t];
    }
    #pragma unroll
    for (int m = 1; m < 8; m <<= 1) {     // reduce within the 8-lane group
        dot += __shfl_xor(dot, m);
        nn1 += __shfl_xor(nn1, m);
        nn2 += __shfl_xor(nn2, m);
    }

    float denom = fmaxf(__builtin_amdgcn_sqrtf(nn1 * nn2), 1e-8f);
    float w = dot * __builtin_amdgcn_rcpf(denom);
    float omw = 1.0f - w;

    float4 r0, r1;
    r0.x = w*b[0] + omw*a[0]; r0.y = w*b[1] + omw*a[1];
    r0.z = w*b[2] + omw*a[2]; r0.w = w*b[3] + omw*a[3];
    r1.x = w*b[4] + omw*a[4]; r1.y = w*b[5] + omw*a[5];
    r1.z = w*b[6] + omw*a[6]; r1.w = w*b[7] + omw*a[7];
    float* po = out + ((size_t)node << 6) + (fl << 3);
    *(float4*)po = r0;
    *(float4*)(po + 4) = r1;
}

// ---- launch -------------------------------------------------------------

extern "C" void kernel_launch(void* const* d_in, const int* in_sizes, int n_in,
                              void* d_out, int out_size, void* d_ws, size_t ws_size,
                              hipStream_t stream) {
    const float* feat = (const float*)d_in[0];
    const int*   eidx = (const int*)d_in[1];
    const int4*  src4 = (const int4*)eidx;
    const int4*  dst4 = (const int4*)(eidx + N_EDGES);

    __half*       feat_h  = (__half*)d_ws;                          // 12.8 MB
    __half*       x1_h    = feat_h + (size_t)N_NODES * D_FEAT;      // 12.8 MB
    unsigned int* tmp1    = (unsigned int*)(x1_h + (size_t)N_NODES * D_FEAT); // 6.4 MB
    int*          csr_src = (int*)(tmp1 + N_EDGES);                 // 6.4 MB
    int*          offsets = csr_src + N_EDGES;                      // 100001
    int*          percnt  = offsets + (N_NODES + 1);                // HIST_WGS*NBC (0.4 MB)
    int*          pexcl   = percnt + HIST_WGS * NBC;                // NBC*HIST_WGS (0.4 MB)
    int*          bhist   = pexcl + NBC * HIST_WGS;                 // NBC
    float*        out     = (float*)d_out;

    k1_hist_cast <<<HIST_WGS + CAST1, 256, 0, stream>>>(feat, feat_h, dst4, percnt);
    k2_colscan   <<<NBC + CAST2,      256, 0, stream>>>(percnt, pexcl, bhist, feat, feat_h);
    k3_bucketize <<<HIST_WGS + CAST3, 512, 0, stream>>>(src4, dst4, bhist, pexcl, tmp1, feat, feat_h);
    k4_bucket_csr<<<NBC + CAST4,      512, 0, stream>>>(tmp1, bhist, offsets, csr_src, feat, feat_h);

    int nblocks = N_NODES / 32;   // 3125 exactly (100000 = 3125*32)
    gather1_kernel<<<nblocks, 256, 0, stream>>>(feat_h, offsets, csr_src, x1_h);
    gather2_finalize_kernel<<<nblocks, 256, 0, stream>>>(x1_h, offsets, csr_src, out);
}